// Round 1
// baseline (239.777 us; speedup 1.0000x reference)
//
#include <hip/hip_runtime.h>

// QuantizedBKCore: tridiagonal resolvent diagonal via two continued-fraction
// sweeps, bit-exact replication of the numpy float32/complex64 reference.
//
// Key requirements for bit-exactness vs ref=np:
//  - numpy complex64 division = Smith's algorithm (branch on |dr|>=|di|),
//    each op a separately-rounded IEEE f32 op -> fp contract OFF everywhere.
//  - rintf == np.rint (round-half-even).
//  - recurrences evaluated in the reference's op order.
// Parallelization: segment each chain; continued fraction is contracting
// (two-step Lipschitz <= 1/4), so a warmup of W=64 steps from carry=0
// bit-merges with the true trajectory long before the segment starts.

#define SEG  128   // segment length per lane
#define WARM 64    // warmup steps (analytic error <= 2^-64; bit-merge certain)

struct C2 { float r, i; };

// numpy CFLOAT_divide (Smith), numerator = (nr, 0), no FMA contraction.
__device__ __forceinline__ C2 npdiv(float nr, float dr, float di) {
  #pragma clang fp contract(off)
  const bool  b   = fabsf(dr) >= fabsf(di);
  const float num = b ? di : dr;
  const float den = b ? dr : di;
  const float rat = num / den;          // correctly-rounded IEEE div
  const float t   = num * rat;
  const float s   = den + t;            // mul + add, NOT fma (numpy has no FMA)
  const float scl = 1.0f / s;           // correctly-rounded IEEE div
  const float u   = nr * scl;
  const float m   = nr * rat;
  const float w   = m * scl;
  C2 o;
  o.r = b ? u : w;        // branch1: (nr + 0*rat)*scl = nr*scl ; branch2: (nr*rat+0)*scl
  o.i = b ? -w : -u;      // branch1: (0 - nr*rat)*scl        ; branch2: (0*rat - nr)*scl
  return o;               // sign-flip-of-product == product-of-sign-flip (exact)
}

// -(clip(h0_diag + fake_quantize(v), -10, 10)); all ops exact-order.
__device__ __forceinline__ float neg_a(float vv, float hd) {
  #pragma clang fp contract(off)
  float q = rintf(vv);                         // round half-even == np.rint
  q = fminf(fmaxf(q, -128.0f), 127.0f);        // clip (exact)
  float he = hd + q;
  he = fminf(fmaxf(he, -10.0f), 10.0f);
  return 0.0f - he;                            // real part of (z - a)
}

// clip(+-100) -> rint -> clip(+-128); exact ops.
__device__ __forceinline__ float fq_out(float x) {
  #pragma clang fp contract(off)
  x = fminf(fmaxf(x, -100.0f), 100.0f);
  x = rintf(x);
  x = fminf(fmaxf(x, -128.0f), 127.0f);
  return x;
}

__global__ void __launch_bounds__(256)
bk_kernel(const float* __restrict__ v,
          const float* __restrict__ hdiag,
          const float* __restrict__ hsub,
          const float* __restrict__ hsup,
          float2* __restrict__ out,      // (B,N) pairs; scratch for R, then final
          int N, int segs_per_row, int B) {
  #pragma clang fp contract(off)
  const int g   = blockIdx.x * blockDim.x + threadIdx.x;
  const int row = g / segs_per_row;
  if (row >= B) return;
  const int seg = g - row * segs_per_row;
  const int s0  = seg * SEG;
  const int s1  = min(s0 + SEG, N);

  const float* vr  = v   + (long)row * N;
  float2*      orr = out + (long)row * N;

  // ---------------- backward sweep: R[k] for k in [s0, s1) ----------------
  // R[N-1]=0; R[k-1] = c[k-1] / (z - a[k] - R[k])
  float cr = 0.0f, ci = 0.0f;                 // carry ~= R[j1] (exact 0 if j1==N-1)
  const int j1 = min(s1 - 1 + WARM, N - 1);
  int k;
  #pragma unroll 4
  for (k = j1; k >= s1; --k) {                // warmup, no stores
    const float negA = neg_a(vr[k], hdiag[k]);
    const float cc   = hsub[k-1] * hsup[k-1];
    const float dr   = negA - cr;             // ((0 - a) - Re carry)
    const float di   = 1.0f - ci;             // ((1 - 0) - Im carry)
    const C2 nc = npdiv(cc, dr, di);
    cr = nc.r; ci = nc.i;
  }
  orr[s1 - 1] = make_float2(cr, ci);          // R[s1-1] (for last seg: (0,0)=R[N-1])
  #pragma unroll 4
  for (k = s1 - 1; k > s0; --k) {
    const float negA = neg_a(vr[k], hdiag[k]);
    const float cc   = hsub[k-1] * hsup[k-1];
    const float dr   = negA - cr;
    const float di   = 1.0f - ci;
    const C2 nc = npdiv(cc, dr, di);
    cr = nc.r; ci = nc.i;
    orr[k - 1] = make_float2(cr, ci);
  }

  // ---------------- forward sweep + combine -------------------------------
  // L[0]=0; L[k+1] = c[k] / (z - a[k] - L[k]);  G = 1 / (((z-a) - L) - R)
  cr = 0.0f; ci = 0.0f;                       // carry ~= L[k0] (exact 0 if k0==0)
  const int k0 = max(s0 - WARM, 0);
  #pragma unroll 4
  for (k = k0; k < s0; ++k) {                 // warmup
    const float negA = neg_a(vr[k], hdiag[k]);
    const float cc   = hsub[k] * hsup[k];
    const float dr   = negA - cr;
    const float di   = 1.0f - ci;
    const C2 nc = npdiv(cc, dr, di);
    cr = nc.r; ci = nc.i;
  }
  #pragma unroll 4
  for (k = s0; k < s1 - 1; ++k) {
    const float negA = neg_a(vr[k], hdiag[k]);
    const float2 R  = orr[k];                 // same-lane write -> read (ordered)
    const float drL = negA - cr;              // (z - a) - L  (real)
    const float diL = 1.0f - ci;              //              (imag)
    const float drf = drL - R.x;              // ... - R
    const float dif = diL - R.y;
    const C2 G = npdiv(1.0f, drf, dif);
    orr[k] = make_float2(fq_out(G.r), fq_out(G.i));
    // advance L (reuses drL/diL subexpressions exactly)
    const float cc = hsub[k] * hsup[k];
    const C2 nc = npdiv(cc, drL, diL);
    cr = nc.r; ci = nc.i;
  }
  { // epilogue k = s1-1: combine only (no advance; avoids c[N-1] OOB)
    k = s1 - 1;
    const float negA = neg_a(vr[k], hdiag[k]);
    const float2 R  = orr[k];
    const float drf = (negA - cr) - R.x;
    const float dif = (1.0f - ci) - R.y;
    const C2 G = npdiv(1.0f, drf, dif);
    orr[k] = make_float2(fq_out(G.r), fq_out(G.i));
  }
}

extern "C" void kernel_launch(void* const* d_in, const int* in_sizes, int n_in,
                              void* d_out, int out_size, void* d_ws, size_t ws_size,
                              hipStream_t stream) {
  const float* v    = (const float*)d_in[0];
  const float* hd   = (const float*)d_in[1];
  const float* hsub = (const float*)d_in[2];
  const float* hsup = (const float*)d_in[3];
  const int N = in_sizes[1];
  const int B = in_sizes[0] / N;
  const int segs = (N + SEG - 1) / SEG;       // 128 for N=16384
  const long lanes = (long)B * segs;          // 65536 -> 1024 waves -> 1/SIMD
  const int block = 256;
  const int grid = (int)((lanes + block - 1) / block);
  bk_kernel<<<grid, block, 0, stream>>>(v, hd, hsub, hsup, (float2*)d_out, N, segs, B);
}